// Round 5
// baseline (321.411 us; speedup 1.0000x reference)
//
#include <hip/hip_runtime.h>
#include <hip/hip_bf16.h>

#define B_ 2
#define T_ 2048
#define D_ 1024
#define H_ 16
#define DH_ 64

typedef __attribute__((ext_vector_type(8))) short bf16x8;
typedef __attribute__((ext_vector_type(4))) short bf16x4;
typedef __attribute__((ext_vector_type(4))) float f32x4;
typedef __attribute__((ext_vector_type(8))) unsigned short u16x8;

__device__ __forceinline__ unsigned short f2bf(float f) {   // RNE fp32->bf16
    unsigned int u = __float_as_uint(f);
    return (unsigned short)((u + 0x7FFFu + ((u >> 16) & 1u)) >> 16);
}

// K=16 bf16 MFMA; guard so the host pass never touches the builtin.
__device__ __forceinline__ f32x4 mfma16(bf16x4 a, bf16x4 b, f32x4 c) {
#if defined(__HIP_DEVICE_COMPILE__)
    return __builtin_amdgcn_mfma_f32_16x16x16bf16_1k(a, b, c, 0, 0, 0);
#else
    return c;
#endif
}

// raw v_exp_f32 (2^x). R2 lesson: plain exp2f() is the PRECISE ocml path
// (denorm guards, ~5 instr, +30% VALU cycles); the builtin is 1 instr.
__device__ __forceinline__ float fast_exp2(float x) {
#if defined(__HIP_DEVICE_COMPILE__)
    return __builtin_amdgcn_exp2f(x);
#else
    return exp2f(x);
#endif
}

// ---------------------------------------------------------------------------
// Launch 1: pure streaming conversions (independent blocks).
//   [0,512)    : k  fp32 -> kb  bf16   (interleaved, coalesced per instr)
//   [512,1024) : x  fp32 -> xb  bf16
//   [1024,1152): Wq fp32 -> wqb bf16
//   [1152,2176): v[b,h,t,dh] -> vt[b,h,dh,t] bf16 (64x64 LDS transpose)
// R1 post-mortem: ~15 us either way; not the lever.
// ---------------------------------------------------------------------------
__global__ __launch_bounds__(256) void conv_kernel(
    const float* __restrict__ k, const float* __restrict__ v,
    const float* __restrict__ x, const float* __restrict__ Wq,
    unsigned short* __restrict__ kb, unsigned short* __restrict__ vt,
    unsigned short* __restrict__ xb, unsigned short* __restrict__ wqb)
{
    __shared__ float Ts[64][65];
    const int tid = threadIdx.x;
    const int bi = blockIdx.x;

    if (bi < 1152) {                      // ---- flat conversions ----
        const float* src;
        unsigned short* dst;
        if (bi < 512)       { src = k  + (size_t)bi * 8192;
                              dst = kb  + (size_t)bi * 8192; }
        else if (bi < 1024) { src = x  + (size_t)(bi - 512) * 8192;
                              dst = xb  + (size_t)(bi - 512) * 8192; }
        else                { src = Wq + (size_t)(bi - 1024) * 8192;
                              dst = wqb + (size_t)(bi - 1024) * 8192; }
        #pragma unroll
        for (int u = 0; u < 8; ++u) {
            const int o = u * 1024 + tid * 4;
            const float4 a = *(const float4*)(src + o);
            ushort4 s;
            s.x = f2bf(a.x); s.y = f2bf(a.y);
            s.z = f2bf(a.z); s.w = f2bf(a.w);
            *(ushort4*)(dst + o) = s;
        }
        return;
    }

    // ---- v transpose+convert ----
    const int idx = bi - 1152;
    const int t0 = (idx & 31) * 64;
    const int hb = idx >> 5;
    const size_t bh = (size_t)(hb >> 4) * H_ + (hb & 15);
    #pragma unroll
    for (int u = 0; u < 4; ++u) {
        const int tr = u * 16 + (tid >> 4);
        const int dc = (tid & 15) * 4;
        const float4 r = *(const float4*)(v + (bh * T_ + t0 + tr) * DH_ + dc);
        Ts[tr][dc + 0] = r.x; Ts[tr][dc + 1] = r.y;
        Ts[tr][dc + 2] = r.z; Ts[tr][dc + 3] = r.w;
    }
    __syncthreads();
    #pragma unroll
    for (int u = 0; u < 4; ++u) {
        const int dh = u * 16 + (tid >> 4);
        const int tc = (tid & 15) * 4;
        ushort4 o;
        o.x = f2bf(Ts[tc + 0][dh]); o.y = f2bf(Ts[tc + 1][dh]);
        o.z = f2bf(Ts[tc + 2][dh]); o.w = f2bf(Ts[tc + 3][dh]);
        *(ushort4*)(vt + (bh * DH_ + dh) * T_ + t0 + tc) = o;
    }
}

// ---------------------------------------------------------------------------
// Launch 2: mega-attention (qproj fused). 1024 blocks, 64 q-rows each,
// 4 waves x 16 rows, 4 blocks/CU resident (16 waves/CU).
//
// R5: PHASE 2 IS LDS-FREE AND BARRIER-FREE. R4 showed the softmax/VALU
// trio was neutral at identical 69 us — the binding constraint is the
// per-tile barrier lockstep + LDS round-trip, not any pipe (MfmaUtil 20%,
// VALUBusy 27%, HBM 12%). K/V per (b,h) is 256 KB each — L1/L2/L3
// resident — and both fragment layouts are contiguous per-lane global
// loads, so waves now read K/V fragments DIRECTLY from cache:
//   K-frag: 16 B/lane dwordx4, 16 rows x 64 B segments (coalesced)
//   V-frag: 8 B/lane, 32-B segments (cache-resident)
// V loads issue before QK so V latency hides under QK+softmax; 4 waves/
// SIMD cover K-load latency. Waves are fully independent after the Qs
// read -> tail smooths at wave granularity. Expected signature:
// SQ_LDS_BANK_CONFLICT 9.2M -> ~1-2M (phase-1 only).
//
// Phase 1 (unchanged): Q^T = Wq_h * x^T, bf16 staged, double-buffered,
//   1 barrier/iter. acc C-layout = Q^T [dh = w*16+l4*4+r][qrow=nt*16+l15];
//   bounced through Qs (overlaid on dead Xs1) -> B-operand Q fragments.
//   Q scale folds in log2(e) (exp2-domain softmax, raw v_exp_f32).
// Kept: R0's heavy-first map, exact defer-max skip, setprio on MFMA.
//
// LDS (36864 B): phase1 Ws0=0, Xs0=9216, Ws1=18432, Xs1=27648; Qs=27648.
// ---------------------------------------------------------------------------
__global__ __launch_bounds__(256, 4) void mega_attn(
    const unsigned short* __restrict__ xb,   // [B,T,D]   bf16
    const unsigned short* __restrict__ wqb,  // [D,D]     bf16
    const unsigned short* __restrict__ kb,   // [B,H,T,DH] bf16
    const unsigned short* __restrict__ vt,   // [B,H,DH,T] bf16
    const float* __restrict__ xg,            // [B,T,D] fp32 (residual)
    float* __restrict__ out)                 // [B,T,D] fp32
{
    __shared__ __align__(16) char lds_raw[36864];
    unsigned short (*Ws0)[72] = (unsigned short(*)[72])(lds_raw);
    unsigned short (*Xs0)[72] = (unsigned short(*)[72])(lds_raw + 9216);
    unsigned short (*Ws1)[72] = (unsigned short(*)[72])(lds_raw + 18432);
    unsigned short (*Xs1)[72] = (unsigned short(*)[72])(lds_raw + 27648);
    unsigned short (*Qs)[72]  = (unsigned short(*)[72])(lds_raw + 27648);

    const int tid = threadIdx.x;
    const int lane = tid & 63;
    const int w = tid >> 6;
    const int l15 = lane & 15, l4 = lane >> 4;
    const int bi = blockIdx.x;

    const int qt = 31 - (bi >> 5);           // R0's proven heavy-first map
    const int hb = bi & 31;
    const int h = hb & 15, b = hb >> 4;
    const int q0 = qt * 64;
    const size_t bh = (size_t)b * H_ + h;

    const int srow = tid >> 2;               // staging row 0..63
    const int scol = (tid & 3) * 16;         // staging col (shorts)

    // ---- Phase 1: Q^T tile build (bf16 staged, dbuf, 1 barrier/iter) ----
    f32x4 acc[4] = {};
    {
        const unsigned short* xg0 = xb  + ((size_t)b * T_ + q0 + srow) * D_ + scol;
        const unsigned short* wg0 = wqb + (size_t)(h * 64 + srow) * D_ + scol;

        // stage iter 0 into buffer 0
        uint4 xr0 = *(const uint4*)(xg0);
        uint4 xr1 = *(const uint4*)(xg0 + 8);
        uint4 wr0 = *(const uint4*)(wg0);
        uint4 wr1 = *(const uint4*)(wg0 + 8);
        *(uint4*)&Xs0[srow][scol] = xr0;
        *(uint4*)&Xs0[srow][scol + 8] = xr1;
        *(uint4*)&Ws0[srow][scol] = wr0;
        *(uint4*)&Ws0[srow][scol + 8] = wr1;
        __syncthreads();

        int p = 0;
        for (int it = 0; it < 16; ++it) {
            if (it < 15) {
                const int kk = (it + 1) * 64;
                xr0 = *(const uint4*)(xg0 + kk);
                xr1 = *(const uint4*)(xg0 + kk + 8);
                wr0 = *(const uint4*)(wg0 + kk);
                wr1 = *(const uint4*)(wg0 + kk + 8);
            }
            unsigned short (*Wp)[72] = p ? Ws1 : Ws0;
            unsigned short (*Xp)[72] = p ? Xs1 : Xs0;
            #pragma unroll
            for (int kc = 0; kc < 2; ++kc) {
                const bf16x8 wf = *(const bf16x8*)&Wp[w * 16 + l15][kc * 32 + l4 * 8];
                #pragma unroll
                for (int nt = 0; nt < 4; ++nt) {
                    const bf16x8 xf = *(const bf16x8*)&Xp[nt * 16 + l15][kc * 32 + l4 * 8];
                    acc[nt] = __builtin_amdgcn_mfma_f32_16x16x32_bf16(wf, xf, acc[nt], 0, 0, 0);
                }
            }
            if (it < 15) {
                unsigned short (*Wn)[72] = p ? Ws0 : Ws1;
                unsigned short (*Xn)[72] = p ? Xs0 : Xs1;
                *(uint4*)&Xn[srow][scol] = xr0;
                *(uint4*)&Xn[srow][scol + 8] = xr1;
                *(uint4*)&Wn[srow][scol] = wr0;
                *(uint4*)&Wn[srow][scol + 8] = wr1;
                __syncthreads();
                p ^= 1;
            }
        }
    }
    __syncthreads();   // final phase-1 buffer (Ws1/Xs1) fully consumed

    // Qs write: acc[nt][r] = Q^T[dh = w*16+l4*4+r][qrow = nt*16+l15]
    // scale folds in log2(e): softmax computed as 2^(s' - m') with
    // s' = s*log2e — weights identical to exp-domain softmax.
    {
        const float qscale = (1.0f / 32.0f) * 1.4426950408889634f;
        #pragma unroll
        for (int nt = 0; nt < 4; ++nt) {
            ushort4 o;
            o.x = f2bf(acc[nt][0] * qscale); o.y = f2bf(acc[nt][1] * qscale);
            o.z = f2bf(acc[nt][2] * qscale); o.w = f2bf(acc[nt][3] * qscale);
            *(ushort4*)&Qs[nt * 16 + l15][w * 16 + l4 * 4] = o;
        }
    }
    __syncthreads();   // all Qs writes visible (cross-wave)

    // Q B-fragments: lane l15 = qrow (w*16+l15), k = dh.
    // No barrier needed after these reads — LDS is dead from here on.
    bf16x8 qf[2];
    #pragma unroll
    for (int kc = 0; kc < 2; ++kc)
        qf[kc] = *(const bf16x8*)&Qs[w * 16 + l15][kc * 32 + l4 * 8];

    // ---- Phase 2: barrier-free flash loop, K/V direct from cache ----
    f32x4 o_acc[4] = {};                     // O^T: dh = mt*16+l4*4+r, qrow = l15
    float m_i = -INFINITY, l_i = 0.0f;

    const unsigned short* kbase = kb + bh * (size_t)T_ * DH_;
    const unsigned short* vbase = vt + bh * (size_t)DH_ * T_;

    for (int j0 = 0; j0 <= q0; j0 += 64) {
        // K fragments: lane = key (j0 + nt*16 + l15), dh = kc*32 + l4*8 (16 B)
        bf16x8 kf[2][4];
        #pragma unroll
        for (int kc = 0; kc < 2; ++kc)
            #pragma unroll
            for (int nt = 0; nt < 4; ++nt)
                kf[kc][nt] = *(const bf16x8*)(
                    kbase + (size_t)(j0 + nt * 16 + l15) * DH_ + kc * 32 + l4 * 8);

        // V fragments issued now: latency hides under QK + softmax.
        // lane = dh (mt*16 + l15), keys j0 + c*16 + l4*4 .. +3 (8 B)
        bf16x4 vf[4][4];
        #pragma unroll
        for (int c = 0; c < 4; ++c)
            #pragma unroll
            for (int mt = 0; mt < 4; ++mt)
                vf[c][mt] = *(const bf16x4*)(
                    vbase + (size_t)(mt * 16 + l15) * T_ + j0 + c * 16 + l4 * 4);

        // S^T = K * Q^T : st[nt] keys nt*16 + l4*4+r, qrow = w*16+l15
        f32x4 st[4] = {};
        __builtin_amdgcn_s_setprio(1);
        #pragma unroll
        for (int kc = 0; kc < 2; ++kc) {
            #pragma unroll
            for (int nt = 0; nt < 4; ++nt)
                st[nt] = __builtin_amdgcn_mfma_f32_16x16x32_bf16(kf[kc][nt], qf[kc], st[nt], 0, 0, 0);
        }
        __builtin_amdgcn_s_setprio(0);

        // causal mask (diagonal tile only)
        if (j0 == q0) {
            const int thr = w * 16 + l15 - l4 * 4;   // mask if nt*16+r > thr
            #pragma unroll
            for (int nt = 0; nt < 4; ++nt)
                #pragma unroll
                for (int r = 0; r < 4; ++r)
                    if (nt * 16 + r > thr) st[nt][r] = -INFINITY;
        }

        // online softmax (exp2 domain): 16 in-lane values + 2-shfl butterfly
        float rm = -INFINITY;
        #pragma unroll
        for (int nt = 0; nt < 4; ++nt)
            #pragma unroll
            for (int r = 0; r < 4; ++r) rm = fmaxf(rm, st[nt][r]);
        rm = fmaxf(rm, __shfl_xor(rm, 16));
        rm = fmaxf(rm, __shfl_xor(rm, 32));

        if (__all(rm <= m_i)) {
            // EXACT defer-max skip: mn == m_i, alpha == 1 — no rescale.
            float rs = 0.0f;
            #pragma unroll
            for (int nt = 0; nt < 4; ++nt)
                #pragma unroll
                for (int r = 0; r < 4; ++r) {
                    const float pv = fast_exp2(st[nt][r] - m_i);
                    st[nt][r] = pv;
                    rs += pv;
                }
            rs += __shfl_xor(rs, 16);
            rs += __shfl_xor(rs, 32);
            l_i += rs;
        } else {
            const float mn = fmaxf(m_i, rm);
            const float alpha = fast_exp2(m_i - mn);
            float rs = 0.0f;
            #pragma unroll
            for (int nt = 0; nt < 4; ++nt)
                #pragma unroll
                for (int r = 0; r < 4; ++r) {
                    const float pv = fast_exp2(st[nt][r] - mn);
                    st[nt][r] = pv;
                    rs += pv;
                }
            rs += __shfl_xor(rs, 16);
            rs += __shfl_xor(rs, 32);
            l_i = l_i * alpha + rs;
            m_i = mn;
            #pragma unroll
            for (int mt = 0; mt < 4; ++mt)
                #pragma unroll
                for (int r = 0; r < 4; ++r) o_acc[mt][r] *= alpha;
        }

        // pack P^T into K=16 B-frags (v_perm truncation, 2 vals/op)
        bf16x4 pf[4];
        #pragma unroll
        for (int nt = 0; nt < 4; ++nt) {
            union { unsigned int u[2]; bf16x4 s; } cv;
            cv.u[0] = __builtin_amdgcn_perm(__float_as_uint(st[nt][1]),
                                            __float_as_uint(st[nt][0]), 0x07060302u);
            cv.u[1] = __builtin_amdgcn_perm(__float_as_uint(st[nt][3]),
                                            __float_as_uint(st[nt][2]), 0x07060302u);
            pf[nt] = cv.s;
        }

        // O^T += V^T * P^T  (A = V^T fragments from cache, B = P^T in regs)
        __builtin_amdgcn_s_setprio(1);
        #pragma unroll
        for (int c = 0; c < 4; ++c) {
            #pragma unroll
            for (int mt = 0; mt < 4; ++mt)
                o_acc[mt] = mfma16(vf[c][mt], pf[c], o_acc[mt]);
        }
        __builtin_amdgcn_s_setprio(0);
    }

    // epilogue: out = x + O^T / l   (dh = mt*16 + l4*4+r, qrow = l15)
    const float inv = 1.0f / l_i;
    const int qrow = q0 + w * 16 + l15;
    #pragma unroll
    for (int mt = 0; mt < 4; ++mt) {
        #pragma unroll
        for (int r = 0; r < 4; ++r) {
            const int d = h * DH_ + mt * 16 + l4 * 4 + r;
            const size_t off = ((size_t)b * T_ + qrow) * D_ + d;
            out[off] = xg[off] + o_acc[mt][r] * inv;
        }
    }
}

extern "C" void kernel_launch(void* const* d_in, const int* in_sizes, int n_in,
                              void* d_out, int out_size, void* d_ws, size_t ws_size,
                              hipStream_t stream) {
    const float* x  = (const float*)d_in[0];
    const float* k  = (const float*)d_in[1];
    const float* v  = (const float*)d_in[2];
    const float* Wq = (const float*)d_in[3];
    float* out = (float*)d_out;

    const size_t NE = (size_t)B_ * H_ * T_ * DH_;   // 4M elements
    unsigned short* kb  = (unsigned short*)d_ws;    // 8 MB
    unsigned short* vt  = kb + NE;                  // 8 MB
    unsigned short* xb  = vt + NE;                  // 8 MB
    unsigned short* wqb = xb + NE;                  // 2 MB

    conv_kernel<<<2176, 256, 0, stream>>>(k, v, x, Wq, kb, vt, xb, wqb);
    mega_attn<<<1024, 256, 0, stream>>>(xb, wqb, kb, vt, x, out);
}

// Round 6
// 188.739 us; speedup vs baseline: 1.7029x; 1.7029x over previous
//
#include <hip/hip_runtime.h>
#include <hip/hip_bf16.h>

#define B_ 2
#define T_ 2048
#define D_ 1024
#define H_ 16
#define DH_ 64

typedef __attribute__((ext_vector_type(8))) short bf16x8;
typedef __attribute__((ext_vector_type(4))) short bf16x4;
typedef __attribute__((ext_vector_type(4))) float f32x4;
typedef __attribute__((ext_vector_type(8))) unsigned short u16x8;

__device__ __forceinline__ unsigned short f2bf(float f) {   // RNE fp32->bf16
    unsigned int u = __float_as_uint(f);
    return (unsigned short)((u + 0x7FFFu + ((u >> 16) & 1u)) >> 16);
}

// K=16 bf16 MFMA; guard so the host pass never touches the builtin.
__device__ __forceinline__ f32x4 mfma16(bf16x4 a, bf16x4 b, f32x4 c) {
#if defined(__HIP_DEVICE_COMPILE__)
    return __builtin_amdgcn_mfma_f32_16x16x16bf16_1k(a, b, c, 0, 0, 0);
#else
    return c;
#endif
}

// raw v_exp_f32 (2^x). R2 lesson: plain exp2f() is the PRECISE ocml path
// (denorm guards, ~5 instr, +30% VALU cycles); the builtin is 1 instr.
__device__ __forceinline__ float fast_exp2(float x) {
#if defined(__HIP_DEVICE_COMPILE__)
    return __builtin_amdgcn_exp2f(x);
#else
    return exp2f(x);
#endif
}

// ---------------------------------------------------------------------------
// Launch 1: pure streaming conversions (independent blocks). Unchanged.
//   [0,512)    : k  fp32 -> kb  bf16
//   [512,1024) : x  fp32 -> xb  bf16
//   [1024,1152): Wq fp32 -> wqb bf16
//   [1152,2176): v[b,h,t,dh] -> vt[b,h,dh,t] bf16 (64x64 LDS transpose)
// ---------------------------------------------------------------------------
__global__ __launch_bounds__(256) void conv_kernel(
    const float* __restrict__ k, const float* __restrict__ v,
    const float* __restrict__ x, const float* __restrict__ Wq,
    unsigned short* __restrict__ kb, unsigned short* __restrict__ vt,
    unsigned short* __restrict__ xb, unsigned short* __restrict__ wqb)
{
    __shared__ float Ts[64][65];
    const int tid = threadIdx.x;
    const int bi = blockIdx.x;

    if (bi < 1152) {                      // ---- flat conversions ----
        const float* src;
        unsigned short* dst;
        if (bi < 512)       { src = k  + (size_t)bi * 8192;
                              dst = kb  + (size_t)bi * 8192; }
        else if (bi < 1024) { src = x  + (size_t)(bi - 512) * 8192;
                              dst = xb  + (size_t)(bi - 512) * 8192; }
        else                { src = Wq + (size_t)(bi - 1024) * 8192;
                              dst = wqb + (size_t)(bi - 1024) * 8192; }
        #pragma unroll
        for (int u = 0; u < 8; ++u) {
            const int o = u * 1024 + tid * 4;
            const float4 a = *(const float4*)(src + o);
            ushort4 s;
            s.x = f2bf(a.x); s.y = f2bf(a.y);
            s.z = f2bf(a.z); s.w = f2bf(a.w);
            *(ushort4*)(dst + o) = s;
        }
        return;
    }

    // ---- v transpose+convert ----
    const int idx = bi - 1152;
    const int t0 = (idx & 31) * 64;
    const int hb = idx >> 5;
    const size_t bh = (size_t)(hb >> 4) * H_ + (hb & 15);
    #pragma unroll
    for (int u = 0; u < 4; ++u) {
        const int tr = u * 16 + (tid >> 4);
        const int dc = (tid & 15) * 4;
        const float4 r = *(const float4*)(v + (bh * T_ + t0 + tr) * DH_ + dc);
        Ts[tr][dc + 0] = r.x; Ts[tr][dc + 1] = r.y;
        Ts[tr][dc + 2] = r.z; Ts[tr][dc + 3] = r.w;
    }
    __syncthreads();
    #pragma unroll
    for (int u = 0; u < 4; ++u) {
        const int dh = u * 16 + (tid >> 4);
        const int tc = (tid & 15) * 4;
        ushort4 o;
        o.x = f2bf(Ts[tc + 0][dh]); o.y = f2bf(Ts[tc + 1][dh]);
        o.z = f2bf(Ts[tc + 2][dh]); o.w = f2bf(Ts[tc + 3][dh]);
        *(ushort4*)(vt + (bh * DH_ + dh) * T_ + t0 + tc) = o;
    }
}

// ---------------------------------------------------------------------------
// Launch 2: mega-attention. 1024 blocks, 64 q-rows, 4 waves x 16 rows.
//
// R6: DUAL-CHAIN FLASH (T15 ILP-2). R5 proved LDS staging must stay
// (direct-from-cache was 3.4x slower: 4x redundant VMEM + 4KB-stride V).
// R4 proved the per-tile serial chain (QK MFMA -> serial softmax -> pack
// -> PV -> barrier, ~500-700cy with ~100cy MFMA) is the floor: only 4
// waves/SIMD overlap it -> MfmaUtil ~20%. Fix at fixed occupancy: ILP.
// Each iteration processes TWO key-tiles with fully independent online
// softmax states (mA,lA,oA)/(mB,lB,oB), merged in the epilogue. The two
// QK groups / softmax chains / PV groups are register-independent; PV-A
// is ordered before softmax-B so MFMA overlaps VALU by program order.
// Staging: same 4x9216 LDS buffers, now single-buffered PAIRS (Ks0/Ks1 =
// tiles j,j+64; Vs0/Vs1 same), 2 barriers per 128 keys (same rate as R4).
// K prefetch at iter top, V prefetch mid-compute (both L2-resident).
// Bank math (R5 round): all patterns at pass floor with stride 72;
// SQ_LDS_BANK_CONFLICT ~9.2M is inherent multi-pass, not fixable.
//
// Kept: heavy-first map, exp2-domain softmax (log2e in Q scale) + raw
// v_exp_f32, exact defer-max skip per chain, setprio on MFMA clusters.
//
// LDS (36864 B): phase1 Ws0=0, Xs0=9216, Ws1=18432, Xs1=27648; Qs=27648;
// phase2 Ks0=0, Ks1=9216, Vs0=18432, Vs1=27648. Vs1 overlays Qs -> extra
// barrier between qf read and prologue staging.
// ---------------------------------------------------------------------------
__global__ __launch_bounds__(256, 4) void mega_attn(
    const unsigned short* __restrict__ xb,   // [B,T,D]   bf16
    const unsigned short* __restrict__ wqb,  // [D,D]     bf16
    const unsigned short* __restrict__ kb,   // [B,H,T,DH] bf16
    const unsigned short* __restrict__ vt,   // [B,H,DH,T] bf16
    const float* __restrict__ xg,            // [B,T,D] fp32 (residual)
    float* __restrict__ out)                 // [B,T,D] fp32
{
    __shared__ __align__(16) char lds_raw[36864];
    unsigned short (*Ws0)[72] = (unsigned short(*)[72])(lds_raw);
    unsigned short (*Xs0)[72] = (unsigned short(*)[72])(lds_raw + 9216);
    unsigned short (*Ws1)[72] = (unsigned short(*)[72])(lds_raw + 18432);
    unsigned short (*Xs1)[72] = (unsigned short(*)[72])(lds_raw + 27648);
    unsigned short (*Qs)[72]  = (unsigned short(*)[72])(lds_raw + 27648);
    unsigned short (*Ks0)[72] = (unsigned short(*)[72])(lds_raw);
    unsigned short (*Ks1)[72] = (unsigned short(*)[72])(lds_raw + 9216);
    unsigned short (*Vs0)[72] = (unsigned short(*)[72])(lds_raw + 18432);
    unsigned short (*Vs1)[72] = (unsigned short(*)[72])(lds_raw + 27648);

    const int tid = threadIdx.x;
    const int lane = tid & 63;
    const int w = tid >> 6;
    const int l15 = lane & 15, l4 = lane >> 4;
    const int bi = blockIdx.x;

    const int qt = 31 - (bi >> 5);           // heavy-first map (proven)
    const int hb = bi & 31;
    const int h = hb & 15, b = hb >> 4;
    const int q0 = qt * 64;
    const size_t bh = (size_t)b * H_ + h;

    const int srow = tid >> 2;               // staging row 0..63
    const int scol = (tid & 3) * 16;         // staging col (shorts)

    // ---- Phase 1: Q^T tile build (bf16 staged, dbuf, 1 barrier/iter) ----
    f32x4 acc[4] = {};
    {
        const unsigned short* xg0 = xb  + ((size_t)b * T_ + q0 + srow) * D_ + scol;
        const unsigned short* wg0 = wqb + (size_t)(h * 64 + srow) * D_ + scol;

        uint4 xr0 = *(const uint4*)(xg0);
        uint4 xr1 = *(const uint4*)(xg0 + 8);
        uint4 wr0 = *(const uint4*)(wg0);
        uint4 wr1 = *(const uint4*)(wg0 + 8);
        *(uint4*)&Xs0[srow][scol] = xr0;
        *(uint4*)&Xs0[srow][scol + 8] = xr1;
        *(uint4*)&Ws0[srow][scol] = wr0;
        *(uint4*)&Ws0[srow][scol + 8] = wr1;
        __syncthreads();

        int p = 0;
        for (int it = 0; it < 16; ++it) {
            if (it < 15) {
                const int kk = (it + 1) * 64;
                xr0 = *(const uint4*)(xg0 + kk);
                xr1 = *(const uint4*)(xg0 + kk + 8);
                wr0 = *(const uint4*)(wg0 + kk);
                wr1 = *(const uint4*)(wg0 + kk + 8);
            }
            unsigned short (*Wp)[72] = p ? Ws1 : Ws0;
            unsigned short (*Xp)[72] = p ? Xs1 : Xs0;
            #pragma unroll
            for (int kc = 0; kc < 2; ++kc) {
                const bf16x8 wf = *(const bf16x8*)&Wp[w * 16 + l15][kc * 32 + l4 * 8];
                #pragma unroll
                for (int nt = 0; nt < 4; ++nt) {
                    const bf16x8 xf = *(const bf16x8*)&Xp[nt * 16 + l15][kc * 32 + l4 * 8];
                    acc[nt] = __builtin_amdgcn_mfma_f32_16x16x32_bf16(wf, xf, acc[nt], 0, 0, 0);
                }
            }
            if (it < 15) {
                unsigned short (*Wn)[72] = p ? Ws0 : Ws1;
                unsigned short (*Xn)[72] = p ? Xs0 : Xs1;
                *(uint4*)&Xn[srow][scol] = xr0;
                *(uint4*)&Xn[srow][scol + 8] = xr1;
                *(uint4*)&Wn[srow][scol] = wr0;
                *(uint4*)&Wn[srow][scol + 8] = wr1;
                __syncthreads();
                p ^= 1;
            }
        }
    }
    __syncthreads();   // final phase-1 buffer fully consumed

    // Qs write: acc[nt][r] = Q^T[dh = w*16+l4*4+r][qrow = nt*16+l15]
    {
        const float qscale = (1.0f / 32.0f) * 1.4426950408889634f;  // 1/sqrt(D)*log2e
        #pragma unroll
        for (int nt = 0; nt < 4; ++nt) {
            ushort4 o;
            o.x = f2bf(acc[nt][0] * qscale); o.y = f2bf(acc[nt][1] * qscale);
            o.z = f2bf(acc[nt][2] * qscale); o.w = f2bf(acc[nt][3] * qscale);
            *(ushort4*)&Qs[nt * 16 + l15][w * 16 + l4 * 4] = o;
        }
    }
    __syncthreads();   // all Qs writes visible

    // Q B-fragments: lane l15 = qrow (w*16+l15), k = dh
    bf16x8 qf[2];
    #pragma unroll
    for (int kc = 0; kc < 2; ++kc)
        qf[kc] = *(const bf16x8*)&Qs[w * 16 + l15][kc * 32 + l4 * 8];

    __syncthreads();   // qf reads complete before Vs1 (=Qs overlay) write

    // ---- Phase 2: dual-chain flash, 2 key-tiles per iteration ----
    f32x4 oA[4] = {}, oB[4] = {};
    float mA = -INFINITY, lA = 0.0f;
    float mB = -INFINITY, lB = 0.0f;

    // prologue: stage tiles (0, 64-if-valid) into the pair buffers
    {
        const int jB0 = (q0 >= 64) ? 64 : 0;
        const unsigned short* gk0 = kb + (bh * T_ + srow) * DH_ + scol;
        *(uint4*)&Ks0[srow][scol]     = *(const uint4*)gk0;
        *(uint4*)&Ks0[srow][scol + 8] = *(const uint4*)(gk0 + 8);
        const unsigned short* gk1 = kb + (bh * T_ + jB0 + srow) * DH_ + scol;
        *(uint4*)&Ks1[srow][scol]     = *(const uint4*)gk1;
        *(uint4*)&Ks1[srow][scol + 8] = *(const uint4*)(gk1 + 8);
        const unsigned short* gv0 = vt + (bh * DH_ + srow) * T_ + scol;
        *(uint4*)&Vs0[srow][scol]     = *(const uint4*)gv0;
        *(uint4*)&Vs0[srow][scol + 8] = *(const uint4*)(gv0 + 8);
        const unsigned short* gv1 = vt + (bh * DH_ + srow) * T_ + jB0 + scol;
        *(uint4*)&Vs1[srow][scol]     = *(const uint4*)gv1;
        *(uint4*)&Vs1[srow][scol + 8] = *(const uint4*)(gv1 + 8);
    }
    __syncthreads();

    const int thr = w * 16 + l15 - l4 * 4;   // diag mask: nt*16+r > thr

    for (int j0 = 0; j0 <= q0; j0 += 128) {
        const int jB = j0 + 64;
        const bool bValid = (jB <= q0);
        const bool more = (j0 + 128 <= q0);
        const int jnA = more ? j0 + 128 : 0;
        const int jnB = (j0 + 192 <= q0) ? j0 + 192 : 0;

        // K prefetch for the next pair (issued early; L2-resident)
        uint4 pk0, pk1, pk2, pk3;
        {
            const unsigned short* g0 = kb + (bh * T_ + jnA + srow) * DH_ + scol;
            pk0 = *(const uint4*)g0; pk1 = *(const uint4*)(g0 + 8);
            const unsigned short* g1 = kb + (bh * T_ + jnB + srow) * DH_ + scol;
            pk2 = *(const uint4*)g1; pk3 = *(const uint4*)(g1 + 8);
        }

        // S^T = K * Q^T, both chains (independent MFMA groups)
        f32x4 stA[4] = {}, stB[4] = {};
        __builtin_amdgcn_s_setprio(1);
        #pragma unroll
        for (int kc = 0; kc < 2; ++kc) {
            #pragma unroll
            for (int nt = 0; nt < 4; ++nt) {
                const bf16x8 kfA = *(const bf16x8*)&Ks0[nt * 16 + l15][kc * 32 + l4 * 8];
                stA[nt] = __builtin_amdgcn_mfma_f32_16x16x32_bf16(kfA, qf[kc], stA[nt], 0, 0, 0);
            }
        }
        if (bValid) {
            #pragma unroll
            for (int kc = 0; kc < 2; ++kc) {
                #pragma unroll
                for (int nt = 0; nt < 4; ++nt) {
                    const bf16x8 kfB = *(const bf16x8*)&Ks1[nt * 16 + l15][kc * 32 + l4 * 8];
                    stB[nt] = __builtin_amdgcn_mfma_f32_16x16x32_bf16(kfB, qf[kc], stB[nt], 0, 0, 0);
                }
            }
        }
        __builtin_amdgcn_s_setprio(0);

        // causal masks (diagonal tile lands in A for even qt, B for odd)
        if (j0 == q0) {
            #pragma unroll
            for (int nt = 0; nt < 4; ++nt)
                #pragma unroll
                for (int r = 0; r < 4; ++r)
                    if (nt * 16 + r > thr) stA[nt][r] = -INFINITY;
        }
        if (bValid && jB == q0) {
            #pragma unroll
            for (int nt = 0; nt < 4; ++nt)
                #pragma unroll
                for (int r = 0; r < 4; ++r)
                    if (nt * 16 + r > thr) stB[nt][r] = -INFINITY;
        }

        // ---- chain A softmax (exp2 domain, exact defer-max skip) ----
        {
            float rm = -INFINITY;
            #pragma unroll
            for (int nt = 0; nt < 4; ++nt)
                #pragma unroll
                for (int r = 0; r < 4; ++r) rm = fmaxf(rm, stA[nt][r]);
            rm = fmaxf(rm, __shfl_xor(rm, 16));
            rm = fmaxf(rm, __shfl_xor(rm, 32));
            if (__all(rm <= mA)) {
                float rs = 0.0f;
                #pragma unroll
                for (int nt = 0; nt < 4; ++nt)
                    #pragma unroll
                    for (int r = 0; r < 4; ++r) {
                        const float pv = fast_exp2(stA[nt][r] - mA);
                        stA[nt][r] = pv;
                        rs += pv;
                    }
                rs += __shfl_xor(rs, 16);
                rs += __shfl_xor(rs, 32);
                lA += rs;
            } else {
                const float mn = fmaxf(mA, rm);
                const float alpha = fast_exp2(mA - mn);
                float rs = 0.0f;
                #pragma unroll
                for (int nt = 0; nt < 4; ++nt)
                    #pragma unroll
                    for (int r = 0; r < 4; ++r) {
                        const float pv = fast_exp2(stA[nt][r] - mn);
                        stA[nt][r] = pv;
                        rs += pv;
                    }
                rs += __shfl_xor(rs, 16);
                rs += __shfl_xor(rs, 32);
                lA = lA * alpha + rs;
                mA = mn;
                #pragma unroll
                for (int mt = 0; mt < 4; ++mt)
                    #pragma unroll
                    for (int r = 0; r < 4; ++r) oA[mt][r] *= alpha;
            }
        }

        // pack P^T(A)
        bf16x4 pfA[4];
        #pragma unroll
        for (int nt = 0; nt < 4; ++nt) {
            union { unsigned int u[2]; bf16x4 s; } cv;
            cv.u[0] = __builtin_amdgcn_perm(__float_as_uint(stA[nt][1]),
                                            __float_as_uint(stA[nt][0]), 0x07060302u);
            cv.u[1] = __builtin_amdgcn_perm(__float_as_uint(stA[nt][3]),
                                            __float_as_uint(stA[nt][2]), 0x07060302u);
            pfA[nt] = cv.s;
        }

        // V prefetch for next pair (mid-compute; hides under PV-A/chain B)
        uint4 pv0, pv1, pv2, pv3;
        {
            const unsigned short* g0 = vt + (bh * DH_ + srow) * T_ + jnA + scol;
            pv0 = *(const uint4*)g0; pv1 = *(const uint4*)(g0 + 8);
            const unsigned short* g1 = vt + (bh * DH_ + srow) * T_ + jnB + scol;
            pv2 = *(const uint4*)g1; pv3 = *(const uint4*)(g1 + 8);
        }

        // PV-A (MFMA pipe; overlaps chain-B softmax below via program order)
        __builtin_amdgcn_s_setprio(1);
        #pragma unroll
        for (int c = 0; c < 4; ++c) {
            #pragma unroll
            for (int mt = 0; mt < 4; ++mt) {
                const bf16x4 vfA = *(const bf16x4*)&Vs0[mt * 16 + l15][c * 16 + l4 * 4];
                oA[mt] = mfma16(vfA, pfA[c], oA[mt]);
            }
        }
        __builtin_amdgcn_s_setprio(0);

        if (bValid) {
            // ---- chain B softmax ----
            float rm = -INFINITY;
            #pragma unroll
            for (int nt = 0; nt < 4; ++nt)
                #pragma unroll
                for (int r = 0; r < 4; ++r) rm = fmaxf(rm, stB[nt][r]);
            rm = fmaxf(rm, __shfl_xor(rm, 16));
            rm = fmaxf(rm, __shfl_xor(rm, 32));
            if (__all(rm <= mB)) {
                float rs = 0.0f;
                #pragma unroll
                for (int nt = 0; nt < 4; ++nt)
                    #pragma unroll
                    for (int r = 0; r < 4; ++r) {
                        const float pv = fast_exp2(stB[nt][r] - mB);
                        stB[nt][r] = pv;
                        rs += pv;
                    }
                rs += __shfl_xor(rs, 16);
                rs += __shfl_xor(rs, 32);
                lB += rs;
            } else {
                const float mn = fmaxf(mB, rm);
                const float alpha = fast_exp2(mB - mn);
                float rs = 0.0f;
                #pragma unroll
                for (int nt = 0; nt < 4; ++nt)
                    #pragma unroll
                    for (int r = 0; r < 4; ++r) {
                        const float pv = fast_exp2(stB[nt][r] - mn);
                        stB[nt][r] = pv;
                        rs += pv;
                    }
                rs += __shfl_xor(rs, 16);
                rs += __shfl_xor(rs, 32);
                lB = lB * alpha + rs;
                mB = mn;
                #pragma unroll
                for (int mt = 0; mt < 4; ++mt)
                    #pragma unroll
                    for (int r = 0; r < 4; ++r) oB[mt][r] *= alpha;
            }

            bf16x4 pfB[4];
            #pragma unroll
            for (int nt = 0; nt < 4; ++nt) {
                union { unsigned int u[2]; bf16x4 s; } cv;
                cv.u[0] = __builtin_amdgcn_perm(__float_as_uint(stB[nt][1]),
                                                __float_as_uint(stB[nt][0]), 0x07060302u);
                cv.u[1] = __builtin_amdgcn_perm(__float_as_uint(stB[nt][3]),
                                                __float_as_uint(stB[nt][2]), 0x07060302u);
                pfB[nt] = cv.s;
            }

            __builtin_amdgcn_s_setprio(1);
            #pragma unroll
            for (int c = 0; c < 4; ++c) {
                #pragma unroll
                for (int mt = 0; mt < 4; ++mt) {
                    const bf16x4 vfB = *(const bf16x4*)&Vs1[mt * 16 + l15][c * 16 + l4 * 4];
                    oB[mt] = mfma16(vfB, pfB[c], oB[mt]);
                }
            }
            __builtin_amdgcn_s_setprio(0);
        }

        // re-stage the pair buffers for the next iteration
        if (more) {
            __syncthreads();               // all consumes of this pair done
            *(uint4*)&Ks0[srow][scol]     = pk0;
            *(uint4*)&Ks0[srow][scol + 8] = pk1;
            *(uint4*)&Ks1[srow][scol]     = pk2;
            *(uint4*)&Ks1[srow][scol + 8] = pk3;
            *(uint4*)&Vs0[srow][scol]     = pv0;
            *(uint4*)&Vs0[srow][scol + 8] = pv1;
            *(uint4*)&Vs1[srow][scol]     = pv2;
            *(uint4*)&Vs1[srow][scol + 8] = pv3;
            __syncthreads();               // staged
        }
    }

    // epilogue: merge chains, out = x + O/l
    const float mF = fmaxf(mA, mB);
    const float aA = fast_exp2(mA - mF);
    const float aB = (mB == -INFINITY) ? 0.0f : fast_exp2(mB - mF);
    const float inv = 1.0f / (lA * aA + lB * aB);
    const int qrow = q0 + w * 16 + l15;
    #pragma unroll
    for (int mt = 0; mt < 4; ++mt) {
        #pragma unroll
        for (int r = 0; r < 4; ++r) {
            const int d = h * DH_ + mt * 16 + l4 * 4 + r;
            const size_t off = ((size_t)b * T_ + qrow) * D_ + d;
            out[off] = xg[off] + (oA[mt][r] * aA + oB[mt][r] * aB) * inv;
        }
    }
}

extern "C" void kernel_launch(void* const* d_in, const int* in_sizes, int n_in,
                              void* d_out, int out_size, void* d_ws, size_t ws_size,
                              hipStream_t stream) {
    const float* x  = (const float*)d_in[0];
    const float* k  = (const float*)d_in[1];
    const float* v  = (const float*)d_in[2];
    const float* Wq = (const float*)d_in[3];
    float* out = (float*)d_out;

    const size_t NE = (size_t)B_ * H_ * T_ * DH_;   // 4M elements
    unsigned short* kb  = (unsigned short*)d_ws;    // 8 MB
    unsigned short* vt  = kb + NE;                  // 8 MB
    unsigned short* xb  = vt + NE;                  // 8 MB
    unsigned short* wqb = xb + NE;                  // 2 MB

    conv_kernel<<<2176, 256, 0, stream>>>(k, v, x, Wq, kb, vt, xb, wqb);
    mega_attn<<<1024, 256, 0, stream>>>(xb, wqb, kb, vt, x, out);
}